// Round 1
// 436.888 us; speedup vs baseline: 1.0708x; 1.0708x over previous
//
#include <hip/hip_runtime.h>

typedef short short8 __attribute__((ext_vector_type(8)));
typedef float f32x4 __attribute__((ext_vector_type(4)));

#define DIMS   256
#define KCODES 8192
#define NTOK   32768
#define BM     128
#define BN     128
#define NTILES 64
#define MARGIN 0.75f    // ~18 sigma of bf16 score error (sigma ~0.04)
#define CAP    6144

__device__ __forceinline__ unsigned short f2bf(float f) {
    unsigned u = __builtin_bit_cast(unsigned, f);
    unsigned r = (u + 0x7FFFu + ((u >> 16) & 1u)) >> 16;   // RNE
    return (unsigned short)r;
}
__device__ __forceinline__ unsigned fenc(float f) {        // order-preserving float->uint
    unsigned u = __builtin_bit_cast(unsigned, f);
    return ((int)u >= 0) ? (u | 0x80000000u) : ~u;
}
__device__ __forceinline__ float fdec(unsigned e) {        // inverse of fenc
    unsigned u = (e & 0x80000000u) ? (e ^ 0x80000000u) : ~e;
    return __builtin_bit_cast(float, u);
}
// min over 16 contiguous lanes via DPP row-rotate butterfly (VALU-only, no DS pipe)
template <int CTRL>
__device__ __forceinline__ float ror_min(float x) {
    int xi = __builtin_bit_cast(int, x);
    int r  = __builtin_amdgcn_update_dpp(xi, xi, CTRL, 0xF, 0xF, false);
    return fminf(x, __builtin_bit_cast(float, r));
}
__device__ __forceinline__ float rowmin16(float x) {
    x = ror_min<0x121>(x);   // row_ror:1
    x = ror_min<0x122>(x);   // row_ror:2
    x = ror_min<0x124>(x);   // row_ror:4
    x = ror_min<0x128>(x);   // row_ror:8
    return x;
}

// fused: c2[k] = ||cb[k]||^2 (fp32) and optional fp32->bf16 codebook convert.
__global__ __launch_bounds__(256) void prep_kernel(const float* __restrict__ cb,
                                                   float* __restrict__ c2,
                                                   unsigned short* __restrict__ cbbf,
                                                   int do_conv) {
    int row  = blockIdx.x * 4 + (threadIdx.x >> 6);
    int lane = threadIdx.x & 63;
    float4 v = *(const float4*)(cb + (size_t)row * DIMS + (size_t)lane * 4);
    if (do_conv) {
        ushort4 s;
        s.x = f2bf(v.x); s.y = f2bf(v.y); s.z = f2bf(v.z); s.w = f2bf(v.w);
        *(ushort4*)(cbbf + (size_t)row * DIMS + (size_t)lane * 4) = s;
    }
    float s = v.x * v.x + v.y * v.y + v.z * v.z + v.w * v.w;
#pragma unroll
    for (int off = 32; off > 0; off >>= 1) s += __shfl_down(s, off);
    if (lane == 0) c2[row] = s;
}

template <bool WSBF>
__global__ __launch_bounds__(512, 2) void vq_main(const float* __restrict__ h,
                                                  const float* __restrict__ cb,
                                                  const unsigned short* __restrict__ cbbf,
                                                  const float* __restrict__ c2g,
                                                  float* __restrict__ out_q,
                                                  float* __restrict__ out_idx) {
    // double-buffered B tile, XOR-swizzled 16B chunks (chunk c8 of row r at c8^(r&7))
    __shared__ __align__(16) unsigned short Bs[2][BN * DIMS];   // 131072 B
    __shared__ unsigned mrun[BM];                               // fenc-encoded running min
    __shared__ unsigned list[CAP];                              // 24576 B
    __shared__ int cnt;

    const int tid  = threadIdx.x;
    const int lane = tid & 63;
    const int wave = tid >> 6;
    const int l15  = lane & 15;
    const int quad = lane >> 4;
    const int wm   = wave >> 2;      // 0..1 : token half
    const int wn   = wave & 3;       // 0..3 : 32-code stripe
    const int tokBase = blockIdx.x * BM;

    if (tid < BM) mrun[tid] = 0xFFFFFFFFu;
    if (tid == 0) cnt = 0;

    // ---- staging geometry (per-thread constants) ----
    const int srow = tid >> 5;           // base row 0..15, +16 per n
    const int sc8  = tid & 31;           // 16B chunk within row
    const int sswz = sc8 ^ (srow & 7);   // (srow+16n)&7 == srow&7 (16n % 8 == 0)

    short8 g[8];
    auto stage_load = [&](int t) {
#pragma unroll
        for (int n = 0; n < 8; n++) {
            const size_t off = (size_t)(t * BN + srow + n * 16) * DIMS + sc8 * 8;
            if constexpr (WSBF) {
                g[n] = *(const short8*)(cbbf + off);
            } else {
                float4 v0 = *(const float4*)(cb + off);
                float4 v1 = *(const float4*)(cb + off + 4);
                short8 s;
                s[0] = f2bf(v0.x); s[1] = f2bf(v0.y); s[2] = f2bf(v0.z); s[3] = f2bf(v0.w);
                s[4] = f2bf(v1.x); s[5] = f2bf(v1.y); s[6] = f2bf(v1.z); s[7] = f2bf(v1.w);
                g[n] = s;
            }
        }
    };
    auto stage_write = [&](int buf) {
        unsigned short* dst = &Bs[buf][srow * DIMS + sswz * 8];
#pragma unroll
        for (int n = 0; n < 8; n++)
            *(short8*)(dst + n * 16 * DIMS) = g[n];
    };

    stage_load(0);   // global latency hides under A-frag conversion below

    // ---- A fragments in registers: wave's 64 tokens x 256 dims (bf16) ----
    short8 afr[4][8];
#pragma unroll
    for (int i = 0; i < 4; i++) {
        const float* base = h + (size_t)(tokBase + wm * 64 + i * 16 + l15) * DIMS + quad * 8;
#pragma unroll
        for (int kk = 0; kk < 8; kk++) {
            float4 v0 = *(const float4*)(base + kk * 32);
            float4 v1 = *(const float4*)(base + kk * 32 + 4);
            short8 s;
            s[0] = f2bf(v0.x); s[1] = f2bf(v0.y); s[2] = f2bf(v0.z); s[3] = f2bf(v0.w);
            s[4] = f2bf(v1.x); s[5] = f2bf(v1.y); s[6] = f2bf(v1.z); s[7] = f2bf(v1.w);
            afr[i][kk] = s;
        }
    }

    stage_write(0);

    // ---- B read geometry under the XOR swizzle ----
    const int bswz = l15 & 7;                    // row&7 for rows wn*32+l15 and +16
    const int bq   = (quad ^ (bswz & 3)) << 3;   // elem offset within row
    const int bx4  = (bswz & 4) << 3;            // 0 or 32 elems, XORed against kk*32

    // ---- main loop: 64 tiles + redo of tile 0; ONE barrier per tile ----
#pragma unroll 1
    for (int it = 0; it <= NTILES; ++it) {
        const int t = (it == NTILES) ? 0 : it;
        __syncthreads();   // buf[it&1] staged (prev iter writes); mrun of tiles < it complete
        const int cur = it & 1;
        if (it < NTILES) stage_load((it + 1 == NTILES) ? 0 : it + 1);

        const float cc0 = c2g[t * BN + wn * 32 + l15];
        const float cc1 = c2g[t * BN + wn * 32 + 16 + l15];

        const unsigned short* bp = &Bs[cur][(wn * 32 + l15) * DIMS + bq];

        f32x4 acc[4][2];
#pragma unroll
        for (int i = 0; i < 4; i++) { acc[i][0] = (f32x4){0,0,0,0}; acc[i][1] = (f32x4){0,0,0,0}; }

        __builtin_amdgcn_s_setprio(1);
#pragma unroll
        for (int kk = 0; kk < 8; kk++) {
            const int off = (kk * 32) ^ bx4;
            short8 b0 = *(const short8*)(bp + off);
            short8 b1 = *(const short8*)(bp + off + 16 * DIMS);
#pragma unroll
            for (int i = 0; i < 4; i++) {
                acc[i][0] = __builtin_amdgcn_mfma_f32_16x16x32_bf16(afr[i][kk], b0, acc[i][0], 0, 0, 0);
                acc[i][1] = __builtin_amdgcn_mfma_f32_16x16x32_bf16(afr[i][kk], b1, acc[i][1], 0, 0, 0);
            }
        }
        __builtin_amdgcn_s_setprio(0);

        // scores, candidate emission (threshold from mrun), per-token tile-min -> atomicMin
        const int code0 = t * BN + wn * 32 + l15;
#pragma unroll
        for (int i = 0; i < 4; i++) {
            const int tokb = wm * 64 + i * 16 + quad * 4;
            float thr0 = 0, thr1 = 0, thr2 = 0, thr3 = 0;
            if (it > 0) {
                thr0 = fdec(mrun[tokb + 0]) + MARGIN;
                thr1 = fdec(mrun[tokb + 1]) + MARGIN;
                thr2 = fdec(mrun[tokb + 2]) + MARGIN;
                thr3 = fdec(mrun[tokb + 3]) + MARGIN;
            }
            float vm0 = 3.4e38f, vm1 = 3.4e38f, vm2 = 3.4e38f, vm3 = 3.4e38f;
#pragma unroll
            for (int j = 0; j < 2; j++) {
                const float cc = j ? cc1 : cc0;
                const int code = j ? code0 + 16 : code0;
                float s0 = fmaf(-2.f, acc[i][j][0], cc);
                float s1 = fmaf(-2.f, acc[i][j][1], cc);
                float s2 = fmaf(-2.f, acc[i][j][2], cc);
                float s3 = fmaf(-2.f, acc[i][j][3], cc);
                vm0 = fminf(vm0, s0); vm1 = fminf(vm1, s1);
                vm2 = fminf(vm2, s2); vm3 = fminf(vm3, s3);
                if (it > 0) {
                    if (s0 <= thr0) { int p = atomicAdd(&cnt, 1); if (p < CAP) list[p] = (unsigned)(((tokb + 0) << 13) | code); }
                    if (s1 <= thr1) { int p = atomicAdd(&cnt, 1); if (p < CAP) list[p] = (unsigned)(((tokb + 1) << 13) | code); }
                    if (s2 <= thr2) { int p = atomicAdd(&cnt, 1); if (p < CAP) list[p] = (unsigned)(((tokb + 2) << 13) | code); }
                    if (s3 <= thr3) { int p = atomicAdd(&cnt, 1); if (p < CAP) list[p] = (unsigned)(((tokb + 3) << 13) | code); }
                }
            }
            if (it < NTILES) {
                vm0 = rowmin16(vm0); vm1 = rowmin16(vm1);
                vm2 = rowmin16(vm2); vm3 = rowmin16(vm3);
                if (l15 == 0) {
                    atomicMin(&mrun[tokb + 0], fenc(vm0));
                    atomicMin(&mrun[tokb + 1], fenc(vm1));
                    atomicMin(&mrun[tokb + 2], fenc(vm2));
                    atomicMin(&mrun[tokb + 3], fenc(vm3));
                }
            }
        }
        if (it < NTILES) stage_write(cur ^ 1);   // next-tile data -> other buffer
    }
    __syncthreads();   // list/cnt final; Bs free for overlay

    // ---- exact fp32 rescore of candidates (best64 overlays Bs) ----
    unsigned long long* best64 = (unsigned long long*)&Bs[0][0];
    if (tid < BM) best64[tid] = ~0ULL;
    __syncthreads();

    int n = cnt; if (n > CAP) n = CAP;
    for (int p = wave; p < n; p += 8) {
        unsigned e = list[p];
        int tok = (int)(e >> 13), code = (int)(e & 8191);
        float4 hv = *(const float4*)(h + (size_t)(tokBase + tok) * DIMS + lane * 4);
        float4 cv = *(const float4*)(cb + (size_t)code * DIMS + lane * 4);
        float d = hv.x * cv.x + hv.y * cv.y + hv.z * cv.z + hv.w * cv.w;
#pragma unroll
        for (int m = 1; m < 64; m <<= 1) d += __shfl_xor(d, m);
        float s = c2g[code] - 2.f * d;
        if (lane == 0)
            atomicMin(&best64[tok], ((unsigned long long)fenc(s) << 32) | (unsigned)code);
    }
    __syncthreads();

    if (tid < BM)
        out_idx[tokBase + tid] = (float)(unsigned)(best64[tid] & 0xFFFFFFFFULL);
#pragma unroll
    for (int e = tid; e < BM * (DIMS / 4); e += 512) {
        int r = e >> 6, c4 = e & 63;
        int idx = (int)(unsigned)(best64[r] & 0xFFFFFFFFULL);
        float4 v = *(const float4*)(cb + (size_t)idx * DIMS + c4 * 4);
        *(float4*)(out_q + (size_t)(tokBase + r) * DIMS + c4 * 4) = v;
    }
}

extern "C" void kernel_launch(void* const* d_in, const int* in_sizes, int n_in,
                              void* d_out, int out_size, void* d_ws, size_t ws_size,
                              hipStream_t stream) {
    const float* h  = (const float*)d_in[0];   // [32768, 256]
    const float* cb = (const float*)d_in[1];   // [8192, 256]
    float* out_q   = (float*)d_out;
    float* out_idx = (float*)d_out + (size_t)NTOK * DIMS;

    float* c2 = (float*)d_ws;                                       // 32 KB
    unsigned short* cbbf = (unsigned short*)((char*)d_ws + 32768);  // 4 MB
    const size_t needed = 32768 + (size_t)KCODES * DIMS * 2;
    const int wsbf = (ws_size >= needed) ? 1 : 0;

    prep_kernel<<<KCODES / 4, 256, 0, stream>>>(cb, c2, cbbf, wsbf);
    if (wsbf)
        vq_main<true><<<NTOK / BM, 512, 0, stream>>>(h, cb, cbbf, c2, out_q, out_idx);
    else
        vq_main<false><<<NTOK / BM, 512, 0, stream>>>(h, cb, (const unsigned short*)nullptr, c2, out_q, out_idx);
}

// Round 2
// 397.089 us; speedup vs baseline: 1.1782x; 1.1002x over previous
//
#include <hip/hip_runtime.h>

typedef short short8 __attribute__((ext_vector_type(8)));
typedef float f32x4 __attribute__((ext_vector_type(4)));

#define DIMS   256
#define KCODES 8192
#define NTOK   32768
#define BM     128
#define BN     128
#define NTILES 64
#define MARGIN 0.75f    // ~18 sigma of bf16 score error (sigma ~0.04)
#define CAP    6144

__device__ __forceinline__ unsigned short f2bf(float f) {
    unsigned u = __builtin_bit_cast(unsigned, f);
    unsigned r = (u + 0x7FFFu + ((u >> 16) & 1u)) >> 16;   // RNE
    return (unsigned short)r;
}
__device__ __forceinline__ unsigned fenc(float f) {        // order-preserving float->uint
    unsigned u = __builtin_bit_cast(unsigned, f);
    return ((int)u >= 0) ? (u | 0x80000000u) : ~u;
}
__device__ __forceinline__ float fdec(unsigned e) {        // inverse of fenc
    unsigned u = (e & 0x80000000u) ? (e ^ 0x80000000u) : ~e;
    return __builtin_bit_cast(float, u);
}

// fused: c2[k] = ||cb[k]||^2 (fp32) and optional fp32->bf16 codebook convert.
__global__ __launch_bounds__(256) void prep_kernel(const float* __restrict__ cb,
                                                   float* __restrict__ c2,
                                                   unsigned short* __restrict__ cbbf,
                                                   int do_conv) {
    int row  = blockIdx.x * 4 + (threadIdx.x >> 6);
    int lane = threadIdx.x & 63;
    float4 v = *(const float4*)(cb + (size_t)row * DIMS + (size_t)lane * 4);
    if (do_conv) {
        ushort4 s;
        s.x = f2bf(v.x); s.y = f2bf(v.y); s.z = f2bf(v.z); s.w = f2bf(v.w);
        *(ushort4*)(cbbf + (size_t)row * DIMS + (size_t)lane * 4) = s;
    }
    float s = v.x * v.x + v.y * v.y + v.z * v.z + v.w * v.w;
#pragma unroll
    for (int off = 32; off > 0; off >>= 1) s += __shfl_down(s, off);
    if (lane == 0) c2[row] = s;
}

template <bool WSBF>
__global__ __launch_bounds__(512, 2) void vq_main(const float* __restrict__ h,
                                                  const float* __restrict__ cb,
                                                  const unsigned short* __restrict__ cbbf,
                                                  const float* __restrict__ c2g,
                                                  float* __restrict__ out_q,
                                                  float* __restrict__ out_idx) {
    // double-buffered B tile, XOR-swizzled 16B chunks (chunk c8 of row r at c8^(r&7))
    __shared__ __align__(16) unsigned short Bs[2][BN * DIMS];   // 131072 B
    __shared__ unsigned mrun[BM];                               // fenc-encoded running min
    __shared__ unsigned list[CAP];                              // 24576 B
    __shared__ int cnt;

    const int tid  = threadIdx.x;
    const int lane = tid & 63;
    const int wave = tid >> 6;
    const int l15  = lane & 15;
    const int quad = lane >> 4;
    const int wm   = wave >> 2;      // 0..1 : token half
    const int wn   = wave & 3;       // 0..3 : 32-code stripe
    const int tokBase = blockIdx.x * BM;

    if (tid < BM) mrun[tid] = 0xFFFFFFFFu;
    if (tid == 0) cnt = 0;

    // ---- staging geometry (per-thread constants) ----
    const int srow = tid >> 5;           // base row 0..15, +16 per n
    const int sc8  = tid & 31;           // 16B chunk within row
    const int sswz = sc8 ^ (srow & 7);   // (srow+16n)&7 == srow&7

    short8 g[8];
    auto stage_load = [&](int t) {
#pragma unroll
        for (int n = 0; n < 8; n++) {
            const size_t off = (size_t)(t * BN + srow + n * 16) * DIMS + sc8 * 8;
            if constexpr (WSBF) {
                g[n] = *(const short8*)(cbbf + off);
            } else {
                float4 v0 = *(const float4*)(cb + off);
                float4 v1 = *(const float4*)(cb + off + 4);
                short8 s;
                s[0] = f2bf(v0.x); s[1] = f2bf(v0.y); s[2] = f2bf(v0.z); s[3] = f2bf(v0.w);
                s[4] = f2bf(v1.x); s[5] = f2bf(v1.y); s[6] = f2bf(v1.z); s[7] = f2bf(v1.w);
                g[n] = s;
            }
        }
    };
    auto stage_write = [&](int buf) {
        unsigned short* dst = &Bs[buf][srow * DIMS + sswz * 8];
#pragma unroll
        for (int n = 0; n < 8; n++)
            *(short8*)(dst + n * 16 * DIMS) = g[n];
    };

    stage_load(0);   // global latency hides under A-frag conversion below

    // ---- token fragments in registers: wave's 64 tokens x 256 dims (bf16) ----
    // B-operand layout for 16x16x32: col = l15 (token), k-chunk = quad
    short8 afr[4][8];
#pragma unroll
    for (int i = 0; i < 4; i++) {
        const float* base = h + (size_t)(tokBase + wm * 64 + i * 16 + l15) * DIMS + quad * 8;
#pragma unroll
        for (int kk = 0; kk < 8; kk++) {
            float4 v0 = *(const float4*)(base + kk * 32);
            float4 v1 = *(const float4*)(base + kk * 32 + 4);
            short8 s;
            s[0] = f2bf(v0.x); s[1] = f2bf(v0.y); s[2] = f2bf(v0.z); s[3] = f2bf(v0.w);
            s[4] = f2bf(v1.x); s[5] = f2bf(v1.y); s[6] = f2bf(v1.z); s[7] = f2bf(v1.w);
            afr[i][kk] = s;
        }
    }

    stage_write(0);

    // ---- B(codes) read geometry under the XOR swizzle (A-operand: row = l15) ----
    const int bswz = l15 & 7;
    const int bq   = (quad ^ (bswz & 3)) << 3;
    const int bx4  = (bswz & 4) << 3;

    // ---- main loop: 64 tiles + redo of tile 0; ONE barrier per tile ----
#pragma unroll 1
    for (int it = 0; it <= NTILES; ++it) {
        const int t = (it == NTILES) ? 0 : it;
        __syncthreads();   // buf[it&1] staged; mrun of tiles < it visible
        const int cur = it & 1;
        if (it < NTILES) stage_load((it + 1 == NTILES) ? 0 : it + 1);

        // per-lane thresholds (stale-safe: staler = larger = more emissions = still correct)
        float thr[4];
        const bool haveThr = (it > 0);
        if (haveThr) {
#pragma unroll
            for (int i = 0; i < 4; i++)
                thr[i] = fdec(mrun[wm * 64 + i * 16 + l15]) + MARGIN;
        }
        // c2 for this lane's 8 codes (reused across all i)
        const int cbase = t * BN + wn * 32;
        const float4 cc0 = *(const float4*)(c2g + cbase + quad * 4);
        const float4 cc1 = *(const float4*)(c2g + cbase + 16 + quad * 4);

        const unsigned short* bp = &Bs[cur][(wn * 32 + l15) * DIMS + bq];

        f32x4 acc[4][2];
#pragma unroll
        for (int i = 0; i < 4; i++) { acc[i][0] = (f32x4){0,0,0,0}; acc[i][1] = (f32x4){0,0,0,0}; }

        __builtin_amdgcn_s_setprio(1);
#pragma unroll
        for (int kk = 0; kk < 8; kk++) {
            const int off = (kk * 32) ^ bx4;
            short8 b0 = *(const short8*)(bp + off);
            short8 b1 = *(const short8*)(bp + off + 16 * DIMS);
#pragma unroll
            for (int i = 0; i < 4; i++) {
                // swapped operands: D = codes^T . tokens -> lane holds 1 token x 8 codes
                acc[i][0] = __builtin_amdgcn_mfma_f32_16x16x32_bf16(b0, afr[i][kk], acc[i][0], 0, 0, 0);
                acc[i][1] = __builtin_amdgcn_mfma_f32_16x16x32_bf16(b1, afr[i][kk], acc[i][1], 0, 0, 0);
            }
        }
        __builtin_amdgcn_s_setprio(0);

        if (it < NTILES) stage_write(cur ^ 1);   // ds_writes drain under the epilogue

        // scores: lane's token = wm*64 + i*16 + l15; codes = cbase + {quad*4+r, 16+quad*4+r}
        const int code00 = cbase + quad * 4;
#pragma unroll
        for (int i = 0; i < 4; i++) {
            const int tok = wm * 64 + i * 16 + l15;
            float s0 = fmaf(-2.f, acc[i][0][0], cc0.x);
            float s1 = fmaf(-2.f, acc[i][0][1], cc0.y);
            float s2 = fmaf(-2.f, acc[i][0][2], cc0.z);
            float s3 = fmaf(-2.f, acc[i][0][3], cc0.w);
            float s4 = fmaf(-2.f, acc[i][1][0], cc1.x);
            float s5 = fmaf(-2.f, acc[i][1][1], cc1.y);
            float s6 = fmaf(-2.f, acc[i][1][2], cc1.z);
            float s7 = fmaf(-2.f, acc[i][1][3], cc1.w);
            float vm = fminf(fminf(fminf(s0, s1), fminf(s2, s3)),
                             fminf(fminf(s4, s5), fminf(s6, s7)));
            if (haveThr) {
                const float th = thr[i];
                const unsigned tk = (unsigned)(tok << 13);
                if (s0 <= th) { int p = atomicAdd(&cnt, 1); if (p < CAP) list[p] = tk | (unsigned)(code00 + 0); }
                if (s1 <= th) { int p = atomicAdd(&cnt, 1); if (p < CAP) list[p] = tk | (unsigned)(code00 + 1); }
                if (s2 <= th) { int p = atomicAdd(&cnt, 1); if (p < CAP) list[p] = tk | (unsigned)(code00 + 2); }
                if (s3 <= th) { int p = atomicAdd(&cnt, 1); if (p < CAP) list[p] = tk | (unsigned)(code00 + 3); }
                if (s4 <= th) { int p = atomicAdd(&cnt, 1); if (p < CAP) list[p] = tk | (unsigned)(code00 + 16); }
                if (s5 <= th) { int p = atomicAdd(&cnt, 1); if (p < CAP) list[p] = tk | (unsigned)(code00 + 17); }
                if (s6 <= th) { int p = atomicAdd(&cnt, 1); if (p < CAP) list[p] = tk | (unsigned)(code00 + 18); }
                if (s7 <= th) { int p = atomicAdd(&cnt, 1); if (p < CAP) list[p] = tk | (unsigned)(code00 + 19); }
            }
            if (it < NTILES) {
                vm = fminf(vm, __shfl_xor(vm, 16));
                vm = fminf(vm, __shfl_xor(vm, 32));
                if (quad == 0) atomicMin(&mrun[tok], fenc(vm));
            }
        }
    }
    __syncthreads();   // list/cnt final; Bs free for overlay

    // ---- exact fp32 rescore of candidates (best64 overlays Bs) ----
    unsigned long long* best64 = (unsigned long long*)&Bs[0][0];
    if (tid < BM) best64[tid] = ~0ULL;
    __syncthreads();

    int n = cnt; if (n > CAP) n = CAP;
    for (int p = wave; p < n; p += 8) {
        unsigned e = list[p];
        int tok = (int)(e >> 13), code = (int)(e & 8191);
        float4 hv = *(const float4*)(h + (size_t)(tokBase + tok) * DIMS + lane * 4);
        float4 cv = *(const float4*)(cb + (size_t)code * DIMS + lane * 4);
        float d = hv.x * cv.x + hv.y * cv.y + hv.z * cv.z + hv.w * cv.w;
#pragma unroll
        for (int m = 1; m < 64; m <<= 1) d += __shfl_xor(d, m);
        float s = c2g[code] - 2.f * d;
        if (lane == 0)
            atomicMin(&best64[tok], ((unsigned long long)fenc(s) << 32) | (unsigned)code);
    }
    __syncthreads();

    if (tid < BM)
        out_idx[tokBase + tid] = (float)(unsigned)(best64[tid] & 0xFFFFFFFFULL);
#pragma unroll
    for (int e = tid; e < BM * (DIMS / 4); e += 512) {
        int r = e >> 6, c4 = e & 63;
        int idx = (int)(unsigned)(best64[r] & 0xFFFFFFFFULL);
        float4 v = *(const float4*)(cb + (size_t)idx * DIMS + c4 * 4);
        *(float4*)(out_q + (size_t)(tokBase + r) * DIMS + c4 * 4) = v;
    }
}

extern "C" void kernel_launch(void* const* d_in, const int* in_sizes, int n_in,
                              void* d_out, int out_size, void* d_ws, size_t ws_size,
                              hipStream_t stream) {
    const float* h  = (const float*)d_in[0];   // [32768, 256]
    const float* cb = (const float*)d_in[1];   // [8192, 256]
    float* out_q   = (float*)d_out;
    float* out_idx = (float*)d_out + (size_t)NTOK * DIMS;

    float* c2 = (float*)d_ws;                                       // 32 KB
    unsigned short* cbbf = (unsigned short*)((char*)d_ws + 32768);  // 4 MB
    const size_t needed = 32768 + (size_t)KCODES * DIMS * 2;
    const int wsbf = (ws_size >= needed) ? 1 : 0;

    prep_kernel<<<KCODES / 4, 256, 0, stream>>>(cb, c2, cbbf, wsbf);
    if (wsbf)
        vq_main<true><<<NTOK / BM, 512, 0, stream>>>(h, cb, cbbf, c2, out_q, out_idx);
    else
        vq_main<false><<<NTOK / BM, 512, 0, stream>>>(h, cb, (const unsigned short*)nullptr, c2, out_q, out_idx);
}

// Round 3
// 362.218 us; speedup vs baseline: 1.2916x; 1.0963x over previous
//
#include <hip/hip_runtime.h>

typedef short short8 __attribute__((ext_vector_type(8)));
typedef float f32x4 __attribute__((ext_vector_type(4)));

#define DIMS   256
#define KCODES 8192
#define NTOK   32768
#define BM     64
#define BN     64
#define NTILES 128
#define MARGIN 0.75f    // ~18 sigma of bf16 score error (sigma ~0.04)
#define CAP    3072     // 48 candidates/token, same per-token budget as before

__device__ __forceinline__ unsigned short f2bf(float f) {
    unsigned u = __builtin_bit_cast(unsigned, f);
    unsigned r = (u + 0x7FFFu + ((u >> 16) & 1u)) >> 16;   // RNE
    return (unsigned short)r;
}
__device__ __forceinline__ unsigned fenc(float f) {        // order-preserving float->uint
    unsigned u = __builtin_bit_cast(unsigned, f);
    return ((int)u >= 0) ? (u | 0x80000000u) : ~u;
}
__device__ __forceinline__ float fdec(unsigned e) {        // inverse of fenc
    unsigned u = (e & 0x80000000u) ? (e ^ 0x80000000u) : ~e;
    return __builtin_bit_cast(float, u);
}

// fused: c2[k] = ||cb[k]||^2 (fp32) and optional fp32->bf16 codebook convert.
__global__ __launch_bounds__(256) void prep_kernel(const float* __restrict__ cb,
                                                   float* __restrict__ c2,
                                                   unsigned short* __restrict__ cbbf,
                                                   int do_conv) {
    int row  = blockIdx.x * 4 + (threadIdx.x >> 6);
    int lane = threadIdx.x & 63;
    float4 v = *(const float4*)(cb + (size_t)row * DIMS + (size_t)lane * 4);
    if (do_conv) {
        ushort4 s;
        s.x = f2bf(v.x); s.y = f2bf(v.y); s.z = f2bf(v.z); s.w = f2bf(v.w);
        *(ushort4*)(cbbf + (size_t)row * DIMS + (size_t)lane * 4) = s;
    }
    float s = v.x * v.x + v.y * v.y + v.z * v.z + v.w * v.w;
#pragma unroll
    for (int off = 32; off > 0; off >>= 1) s += __shfl_down(s, off);
    if (lane == 0) c2[row] = s;
}

template <bool WSBF>
__global__ __launch_bounds__(512, 4) void vq_main(const float* __restrict__ h,
                                                  const float* __restrict__ cb,
                                                  const unsigned short* __restrict__ cbbf,
                                                  const float* __restrict__ c2g,
                                                  float* __restrict__ out_q,
                                                  float* __restrict__ out_idx) {
    // double-buffered 64x256 B tile, XOR-swizzled 16B chunks; ~78 KB total -> 2 blocks/CU
    __shared__ __align__(16) unsigned short Bs[2][BN * DIMS];   // 65536 B
    __shared__ unsigned mrun[BM];                               // fenc-encoded running min
    __shared__ unsigned list[CAP];                              // 12288 B
    __shared__ int cnt;

    const int tid  = threadIdx.x;
    const int lane = tid & 63;
    const int wave = tid >> 6;
    const int l15  = lane & 15;
    const int quad = lane >> 4;
    const int wm   = wave >> 2;      // 0..1 : 32-token half
    const int wn   = wave & 3;       // 0..3 : 16-code stripe
    const int tokBase = blockIdx.x * BM;

    if (tid < BM) mrun[tid] = 0xFFFFFFFFu;
    if (tid == 0) cnt = 0;

    // ---- staging geometry: 32KB tile / 512 threads = 4 x 16B chunks ----
    const int srow = tid >> 5;           // base row 0..15, +16 per n
    const int sc8  = tid & 31;           // 16B chunk within row
    const int sswz = sc8 ^ (srow & 7);   // (srow+16n)&7 == srow&7

    short8 g[4];
    auto stage_load = [&](int t) {
#pragma unroll
        for (int n = 0; n < 4; n++) {
            const size_t off = (size_t)(t * BN + srow + n * 16) * DIMS + sc8 * 8;
            if constexpr (WSBF) {
                g[n] = *(const short8*)(cbbf + off);
            } else {
                float4 v0 = *(const float4*)(cb + off);
                float4 v1 = *(const float4*)(cb + off + 4);
                short8 s;
                s[0] = f2bf(v0.x); s[1] = f2bf(v0.y); s[2] = f2bf(v0.z); s[3] = f2bf(v0.w);
                s[4] = f2bf(v1.x); s[5] = f2bf(v1.y); s[6] = f2bf(v1.z); s[7] = f2bf(v1.w);
                g[n] = s;
            }
        }
    };
    auto stage_write = [&](int buf) {
        unsigned short* dst = &Bs[buf][srow * DIMS + sswz * 8];
#pragma unroll
        for (int n = 0; n < 4; n++)
            *(short8*)(dst + n * 16 * DIMS) = g[n];
    };

    stage_load(0);   // global latency hides under A-frag conversion below

    // ---- token fragments: wave's 32 tokens x 256 dims (bf16), B-operand layout ----
    short8 afr[2][8];
#pragma unroll
    for (int i = 0; i < 2; i++) {
        const float* base = h + (size_t)(tokBase + wm * 32 + i * 16 + l15) * DIMS + quad * 8;
#pragma unroll
        for (int kk = 0; kk < 8; kk++) {
            float4 v0 = *(const float4*)(base + kk * 32);
            float4 v1 = *(const float4*)(base + kk * 32 + 4);
            short8 s;
            s[0] = f2bf(v0.x); s[1] = f2bf(v0.y); s[2] = f2bf(v0.z); s[3] = f2bf(v0.w);
            s[4] = f2bf(v1.x); s[5] = f2bf(v1.y); s[6] = f2bf(v1.z); s[7] = f2bf(v1.w);
            afr[i][kk] = s;
        }
    }

    stage_write(0);

    // ---- codes read geometry under the XOR swizzle (A-operand: row = wn*16+l15) ----
    const int bswz = l15 & 7;                    // (wn*16+l15)&7 == l15&7
    const int bq   = (quad ^ (bswz & 3)) << 3;
    const int bx4  = (bswz & 4) << 3;

    // ---- main loop: 128 tiles + redo of tile 0; ONE barrier per tile ----
#pragma unroll 1
    for (int it = 0; it <= NTILES; ++it) {
        const int t = (it == NTILES) ? 0 : it;
        __syncthreads();   // buf[it&1] staged; mrun of tiles < it visible
        const int cur = it & 1;
        if (it < NTILES) stage_load((it + 1 == NTILES) ? 0 : it + 1);

        float thr[2];
        const bool haveThr = (it > 0);
        if (haveThr) {
#pragma unroll
            for (int i = 0; i < 2; i++)
                thr[i] = fdec(mrun[wm * 32 + i * 16 + l15]) + MARGIN;
        }
        const int cbase  = t * BN + wn * 16;
        const float4 cc  = *(const float4*)(c2g + cbase + quad * 4);

        const unsigned short* bp = &Bs[cur][(wn * 16 + l15) * DIMS + bq];

        f32x4 acc[2];
        acc[0] = (f32x4){0, 0, 0, 0};
        acc[1] = (f32x4){0, 0, 0, 0};

        __builtin_amdgcn_s_setprio(1);
#pragma unroll
        for (int kk = 0; kk < 8; kk++) {
            const int off = (kk * 32) ^ bx4;
            short8 b0 = *(const short8*)(bp + off);
#pragma unroll
            for (int i = 0; i < 2; i++)
                acc[i] = __builtin_amdgcn_mfma_f32_16x16x32_bf16(b0, afr[i][kk], acc[i], 0, 0, 0);
        }
        __builtin_amdgcn_s_setprio(0);

        if (it < NTILES) stage_write(cur ^ 1);   // ds_writes drain under the epilogue

        const int code00 = cbase + quad * 4;
#pragma unroll
        for (int i = 0; i < 2; i++) {
            const int tok = wm * 32 + i * 16 + l15;
            float s0 = fmaf(-2.f, acc[i][0], cc.x);
            float s1 = fmaf(-2.f, acc[i][1], cc.y);
            float s2 = fmaf(-2.f, acc[i][2], cc.z);
            float s3 = fmaf(-2.f, acc[i][3], cc.w);
            float vm = fminf(fminf(s0, s1), fminf(s2, s3));
            if (haveThr) {
                const float th = thr[i];
                const unsigned tk = (unsigned)(tok << 13);
                if (s0 <= th) { int p = atomicAdd(&cnt, 1); if (p < CAP) list[p] = tk | (unsigned)(code00 + 0); }
                if (s1 <= th) { int p = atomicAdd(&cnt, 1); if (p < CAP) list[p] = tk | (unsigned)(code00 + 1); }
                if (s2 <= th) { int p = atomicAdd(&cnt, 1); if (p < CAP) list[p] = tk | (unsigned)(code00 + 2); }
                if (s3 <= th) { int p = atomicAdd(&cnt, 1); if (p < CAP) list[p] = tk | (unsigned)(code00 + 3); }
            }
            if (it < NTILES) {
                vm = fminf(vm, __shfl_xor(vm, 16));
                vm = fminf(vm, __shfl_xor(vm, 32));
                if (quad == 0) atomicMin(&mrun[tok], fenc(vm));
            }
        }
    }
    __syncthreads();   // list/cnt final; Bs free for overlay

    // ---- exact fp32 rescore of candidates (best64 overlays Bs) ----
    unsigned long long* best64 = (unsigned long long*)&Bs[0][0];
    if (tid < BM) best64[tid] = ~0ULL;
    __syncthreads();

    int n = cnt; if (n > CAP) n = CAP;
    for (int p = wave; p < n; p += 8) {
        unsigned e = list[p];
        int tok = (int)(e >> 13), code = (int)(e & 8191);
        float4 hv = *(const float4*)(h + (size_t)(tokBase + tok) * DIMS + lane * 4);
        float4 cv = *(const float4*)(cb + (size_t)code * DIMS + lane * 4);
        float d = hv.x * cv.x + hv.y * cv.y + hv.z * cv.z + hv.w * cv.w;
#pragma unroll
        for (int m = 1; m < 64; m <<= 1) d += __shfl_xor(d, m);
        float s = c2g[code] - 2.f * d;
        if (lane == 0)
            atomicMin(&best64[tok], ((unsigned long long)fenc(s) << 32) | (unsigned)code);
    }
    __syncthreads();

    if (tid < BM)
        out_idx[tokBase + tid] = (float)(unsigned)(best64[tid] & 0xFFFFFFFFULL);
#pragma unroll
    for (int e = tid; e < BM * (DIMS / 4); e += 512) {
        int r = e >> 6, c4 = e & 63;
        int idx = (int)(unsigned)(best64[r] & 0xFFFFFFFFULL);
        float4 v = *(const float4*)(cb + (size_t)idx * DIMS + c4 * 4);
        *(float4*)(out_q + (size_t)(tokBase + r) * DIMS + c4 * 4) = v;
    }
}

extern "C" void kernel_launch(void* const* d_in, const int* in_sizes, int n_in,
                              void* d_out, int out_size, void* d_ws, size_t ws_size,
                              hipStream_t stream) {
    const float* h  = (const float*)d_in[0];   // [32768, 256]
    const float* cb = (const float*)d_in[1];   // [8192, 256]
    float* out_q   = (float*)d_out;
    float* out_idx = (float*)d_out + (size_t)NTOK * DIMS;

    float* c2 = (float*)d_ws;                                       // 32 KB
    unsigned short* cbbf = (unsigned short*)((char*)d_ws + 32768);  // 4 MB
    const size_t needed = 32768 + (size_t)KCODES * DIMS * 2;
    const int wsbf = (ws_size >= needed) ? 1 : 0;

    prep_kernel<<<KCODES / 4, 256, 0, stream>>>(cb, c2, cbbf, wsbf);
    if (wsbf)
        vq_main<true><<<NTOK / BM, 512, 0, stream>>>(h, cb, cbbf, c2, out_q, out_idx);
    else
        vq_main<false><<<NTOK / BM, 512, 0, stream>>>(h, cb, (const unsigned short*)nullptr, c2, out_q, out_idx);
}